// Round 6
// baseline (644.928 us; speedup 1.0000x reference)
//
#include <hip/hip_runtime.h>

#define NEGSLOPE 0.2f
#define NINF (-3.4e38f)

typedef _Float16 half8 __attribute__((ext_vector_type(8)));
typedef _Float16 half2v __attribute__((ext_vector_type(2)));
typedef float f32x4 __attribute__((ext_vector_type(4)));

#define YSTRIDE 72  // f16 units; row stride 144 B (16B-aligned for b128)

// ---------------------------------------------------------------------------
// prep: W1 (384,64) row-major -> B-fragment order for the K=384 fused GEMM.
// (unchanged, known-correct)
// ---------------------------------------------------------------------------
__global__ void prep_w1g(const float* __restrict__ w1, _Float16* __restrict__ w1g) {
    int tid = blockIdx.x * 256 + threadIdx.x;
    if (tid < 24576) {
        int j = tid & 7;
        int L = (tid >> 3) & 63;
        int r = tid >> 9;          // r = ks*4 + t4
        int t4 = r & 3;
        int ks = r >> 2;
        int q = L >> 4, c = L & 15;
        int i = ks >> 1;
        int o = 32 * (ks & 1) + 8 * q + j;
        int u = 16 * t4 + c;
        w1g[tid] = (_Float16)w1[(u * 6 + i) * 64 + o];
    }
}

template <int CTRL>
__device__ __forceinline__ unsigned dpp_mov(unsigned v) {
    return (unsigned)__builtin_amdgcn_update_dpp(0, (int)v, CTRL, 0xF, 0xF, false);
}

// ---------------------------------------------------------------------------
// fused: per wave -- phase 1: top-20 (v4 selection, known-correct) for its
// own 4 points, winners -> LDS iw[edge] (wave-private, no barrier);
// phase 2: edge MLP + K=384 MFMA GEMM + bn1/max/head (R5 structure) with
// XOR-swizzled y tile (o' = o ^ (edge & 0x38)) -> conflict-free LDS writes
// (paired b32) and conflict-free ds_read_b128 A-fragments.
// ---------------------------------------------------------------------------
__global__ __launch_bounds__(128, 3) void fused_kernel(
    const float* __restrict__ x,
    const float* __restrict__ w0, const float* __restrict__ bn0s,
    const float* __restrict__ bn0b, const _Float16* __restrict__ w1g,
    const float* __restrict__ bn1s, const float* __restrict__ bn1b,
    const float* __restrict__ wc, const float* __restrict__ bncs,
    const float* __restrict__ bncb, float* __restrict__ out) {
    __shared__ __align__(16) _Float16 yL[2][80 * YSTRIDE];
    __shared__ __align__(4) _Float16 ehL[2][6][80];
    __shared__ int idxL[2][80];
    const int wave = threadIdx.x >> 6;
    const int lane = threadIdx.x & 63;
    const int q = lane >> 4, c = lane & 15;
    const int gw = blockIdx.x * 2 + wave;     // 0..4095
    const int b = gw >> 9;                    // 512 waves per batch
    const int P0 = (gw & 511) * 4;
    const float* xb = x + b * 6144;
    _Float16* yw = yL[wave];
    _Float16(*ehw)[80] = ehL[wave];
    int* iw = idxL[wave];

    // ==================== phase 1: top-20 per own row ====================
#define REFILL(G)                                                              \
    {                                                                          \
        unsigned long long n1 = 0ull, n2 = 0ull;                               \
        _Pragma("unroll") for (int u = 0; u < 8; ++u) {                        \
            const int T = (G) * 8 + u;                                         \
            const unsigned sv = ((zmask >> T) & 1u) ? 0u : skh[T];             \
            const unsigned long long cc =                                      \
                ((unsigned long long)sv << 32) | (unsigned)(~(T * 64 + lane)); \
            const bool cg = cc > n1;                                           \
            const unsigned long long tt = cg ? n1 : cc;                        \
            n1 = cg ? cc : n1;                                                 \
            if (tt > n2) n2 = tt;                                              \
        }                                                                      \
        g1[(G)] = n1;                                                          \
        g2[(G)] = n2;                                                          \
    }

    for (int r = 0; r < 4; ++r) {
        const int n = P0 + r;
        const float xn0 = xb[n];
        const float xn1 = xb[2048 + n];
        const float xn2 = xb[4096 + n];

        unsigned skh[32];                  // key per candidate t (j=t*64+lane)
        unsigned long long g1[4], g2[4];   // per-group top-2 (key<<32)|~j
#pragma unroll
        for (int gg = 0; gg < 4; ++gg) { g1[gg] = 0ull; g2[gg] = 0ull; }

#pragma unroll
        for (int t = 0; t < 32; ++t) {
            const int j = t * 64 + lane;
            const float dx = xb[j] - xn0;
            const float dy = xb[2048 + j] - xn1;
            const float dz = xb[4096 + j] - xn2;
            const float d = dx * dx + dy * dy + dz * dz;
            const unsigned s = ~__float_as_uint(d);
            skh[t] = s;
            const unsigned long long cand =
                ((unsigned long long)s << 32) | (unsigned)(~j);
            const int gi = t >> 3;
            const bool cgt = cand > g1[gi];
            const unsigned long long t2 = cgt ? g1[gi] : cand;
            g1[gi] = cgt ? cand : g1[gi];
            if (t2 > g2[gi]) g2[gi] = t2;
        }

        unsigned zmask = 0u;

        for (int k = 0; k < 20; ++k) {
            unsigned long long lb = g1[0];
            if (g1[1] > lb) lb = g1[1];
            if (g1[2] > lb) lb = g1[2];
            if (g1[3] > lb) lb = g1[3];
            // 32-bit wave max of key via DPP; lands in lane 63
            unsigned m = (unsigned)(lb >> 32);
            { unsigned o = dpp_mov<0x111>(m); m = o > m ? o : m; }  // shr:1
            { unsigned o = dpp_mov<0x112>(m); m = o > m ? o : m; }  // shr:2
            { unsigned o = dpp_mov<0x114>(m); m = o > m ? o : m; }  // shr:4
            { unsigned o = dpp_mov<0x118>(m); m = o > m ? o : m; }  // shr:8
            { unsigned o = dpp_mov<0x142>(m); m = o > m ? o : m; }  // bcast:15
            { unsigned o = dpp_mov<0x143>(m); m = o > m ? o : m; }  // bcast:31
            const unsigned K = (unsigned)__builtin_amdgcn_readlane((int)m, 63);
            const unsigned long long ball = __ballot((unsigned)(lb >> 32) == K);
            const int Ls = __ffsll((unsigned long long)ball) - 1;
            const unsigned lo =
                (unsigned)__builtin_amdgcn_readlane((int)(unsigned)lb, Ls);
            const int bj = (int)~lo;       // wave-uniform winner index
            if (lane == 0) iw[k * 4 + r] = bj;  // edge order: edge = k*4+pt

            if (k < 19) {
                const bool isL = (lane == Ls);
                const int tstar = bj >> 6;
                const int gstar = bj >> 9;
                zmask |= isL ? (1u << tstar) : 0u;
                unsigned h1;
                switch (gstar) {
                    case 0:
                        if (isL) { g1[0] = g2[0]; g2[0] = 0ull; }
                        h1 = (unsigned)(g1[0] >> 32); break;
                    case 1:
                        if (isL) { g1[1] = g2[1]; g2[1] = 0ull; }
                        h1 = (unsigned)(g1[1] >> 32); break;
                    case 2:
                        if (isL) { g1[2] = g2[2]; g2[2] = 0ull; }
                        h1 = (unsigned)(g1[2] >> 32); break;
                    default:
                        if (isL) { g1[3] = g2[3]; g2[3] = 0ull; }
                        h1 = (unsigned)(g1[3] >> 32); break;
                }
                // rare: winner's bucket depleted -> rebuild its top-2
                if (__builtin_amdgcn_readlane((int)h1, Ls) == 0) {
                    switch (gstar) {
                        case 0: REFILL(0) break;
                        case 1: REFILL(1) break;
                        case 2: REFILL(2) break;
                        default: REFILL(3) break;
                    }
                }
            }
        }
    }
#undef REFILL

    // ==================== phase 2: edge MLP + GEMM ====================
    // e-stage: lane <-> edge_local (and +64 for lanes<16); j from LDS iw
    float e0[6], e1_[6];
    {
        const int n = P0 + (lane & 3);
        const int j = iw[lane];
        const float c0 = xb[n], c1 = xb[2048 + n], c2 = xb[4096 + n];
        e0[0] = xb[j] - c0; e0[1] = xb[2048 + j] - c1; e0[2] = xb[4096 + j] - c2;
        e0[3] = c0; e0[4] = c1; e0[5] = c2;
#pragma unroll
        for (int i = 0; i < 6; ++i) ehw[i][lane] = (_Float16)e0[i];
    }
#pragma unroll
    for (int i = 0; i < 6; ++i) e1_[i] = 0.f;
    if (lane < 16) {
        const int el = 64 + lane;
        const int n = P0 + (lane & 3);
        const int j = iw[el];
        const float c0 = xb[n], c1 = xb[2048 + n], c2 = xb[4096 + n];
        e1_[0] = xb[j] - c0; e1_[1] = xb[2048 + j] - c1; e1_[2] = xb[4096 + j] - c2;
        e1_[3] = c0; e1_[4] = c1; e1_[5] = c2;
#pragma unroll
        for (int i = 0; i < 6; ++i) ehw[i][el] = (_Float16)e1_[i];
    }

    // y-stage: lane = edge, o in pairs; swizzled conflict-free b32 stores
    const int sw0 = lane & 0x38;
    const int sw1 = lane & 8;          // = (64+lane) & 0x38 for lane < 16
#pragma unroll 4
    for (int o = 0; o < 64; o += 2) {
        const float s0a = bn0s[o], b0a = bn0b[o];
        const float s0b = bn0s[o + 1], b0b = bn0b[o + 1];
        const float* wra = w0 + o * 6;
        const float* wrb = wra + 6;
        float ya = wra[0] * e0[0] + wra[1] * e0[1] + wra[2] * e0[2] +
                   wra[3] * e0[3] + wra[4] * e0[4] + wra[5] * e0[5];
        ya = ya * s0a + b0a; ya = fmaxf(ya, NEGSLOPE * ya);
        float yb = wrb[0] * e0[0] + wrb[1] * e0[1] + wrb[2] * e0[2] +
                   wrb[3] * e0[3] + wrb[4] * e0[4] + wrb[5] * e0[5];
        yb = yb * s0b + b0b; yb = fmaxf(yb, NEGSLOPE * yb);
        *(half2v*)&yw[lane * YSTRIDE + (o ^ sw0)] =
            (half2v){(_Float16)ya, (_Float16)yb};
        if (lane < 16) {
            float yc = wra[0] * e1_[0] + wra[1] * e1_[1] + wra[2] * e1_[2] +
                       wra[3] * e1_[3] + wra[4] * e1_[4] + wra[5] * e1_[5];
            yc = yc * s0a + b0a; yc = fmaxf(yc, NEGSLOPE * yc);
            float yd = wrb[0] * e1_[0] + wrb[1] * e1_[1] + wrb[2] * e1_[2] +
                       wrb[3] * e1_[3] + wrb[4] * e1_[4] + wrb[5] * e1_[5];
            yd = yd * s0b + b0b; yd = fmaxf(yd, NEGSLOPE * yd);
            *(half2v*)&yw[(64 + lane) * YSTRIDE + (o ^ sw1)] =
                (half2v){(_Float16)yc, (_Float16)yd};
        }
    }

    __syncthreads();  // cheap safety barrier (waves do similar-length work)

    const half8* w1g8 = (const half8*)w1g;

    f32x4 acc[5][4];  // [m][t4], u = 16*t4 + c, edge row = 4q + r
#pragma unroll
    for (int mm = 0; mm < 5; ++mm)
#pragma unroll
        for (int t4 = 0; t4 < 4; ++t4) acc[mm][t4] = (f32x4){0.f, 0.f, 0.f, 0.f};

    // main loop: 12 k-steps as 6 x 2; A re-read from LDS (swizzled) each step
#pragma unroll 1
    for (int i6 = 0; i6 < 6; ++i6) {
        _Float16 es[5];
#pragma unroll
        for (int mm = 0; mm < 5; ++mm) es[mm] = ehw[i6][16 * mm + c];
#pragma unroll
        for (int ks2 = 0; ks2 < 2; ++ks2) {
            const int ks = 2 * i6 + ks2;
            half8 B[4];
#pragma unroll
            for (int t4 = 0; t4 < 4; ++t4)
                B[t4] = w1g8[(ks * 4 + t4) * 64 + lane];
#pragma unroll
            for (int mm = 0; mm < 5; ++mm) {
                const int row = 16 * mm + c;
                const half8 Af = *(const half8*)&yw[row * YSTRIDE +
                                                    ((32 * ks2 + 8 * q) ^ (row & 0x38))];
                const half8 An = Af * es[mm];
#pragma unroll
                for (int t4 = 0; t4 < 4; ++t4)
                    acc[mm][t4] = __builtin_amdgcn_mfma_f32_16x16x32_f16(
                        An, B[t4], acc[mm][t4], 0, 0, 0);
            }
        }
    }

    // bn1 + leaky + max over k (k = 4m+q)
    float bs1[4], bb1[4];
#pragma unroll
    for (int t4 = 0; t4 < 4; ++t4) {
        bs1[t4] = bn1s[16 * t4 + c];
        bb1[t4] = bn1b[16 * t4 + c];
    }

    float x1[4][4];  // [pt r][t4]
#pragma unroll
    for (int r = 0; r < 4; ++r)
#pragma unroll
        for (int t4 = 0; t4 < 4; ++t4) {
            float v = NINF;
#pragma unroll
            for (int mm = 0; mm < 5; ++mm) {
                float w = acc[mm][t4][r] * bs1[t4] + bb1[t4];
                w = fmaxf(w, NEGSLOPE * w);
                v = fmaxf(v, w);
            }
            v = fmaxf(v, __shfl_xor(v, 16, 64));
            v = fmaxf(v, __shfl_xor(v, 32, 64));
            x1[r][t4] = v;
        }

    // head: z[pt][co] = leaky(bnc(sum_u x1*wc))
    float wcv[3][4];
#pragma unroll
    for (int co = 0; co < 3; ++co)
#pragma unroll
        for (int t4 = 0; t4 < 4; ++t4) wcv[co][t4] = wc[co * 64 + 16 * t4 + c];

    float part[4][3];
#pragma unroll
    for (int r = 0; r < 4; ++r)
#pragma unroll
        for (int co = 0; co < 3; ++co) {
            float s = x1[r][0] * wcv[co][0] + x1[r][1] * wcv[co][1] +
                      x1[r][2] * wcv[co][2] + x1[r][3] * wcv[co][3];
#pragma unroll
            for (int d = 1; d < 16; d <<= 1) s += __shfl_xor(s, d, 64);
            part[r][co] = s;
        }

    if (c == 0 && q < 3) {
        const float sc = bncs[q], bc = bncb[q];
#pragma unroll
        for (int r = 0; r < 4; ++r) {
            float z = part[r][q] * sc + bc;
            z = fmaxf(z, NEGSLOPE * z);
            out[(b * 3 + q) * 2048 + P0 + r] = z;
        }
    }
}

// ---------------------------------------------------------------------------
extern "C" void kernel_launch(void* const* d_in, const int* in_sizes, int n_in,
                              void* d_out, int out_size, void* d_ws, size_t ws_size,
                              hipStream_t stream) {
    const float* x    = (const float*)d_in[0];
    const float* W0   = (const float*)d_in[1];
    const float* bn0s = (const float*)d_in[2];
    const float* bn0b = (const float*)d_in[3];
    const float* W1   = (const float*)d_in[4];
    const float* bn1s = (const float*)d_in[5];
    const float* bn1b = (const float*)d_in[6];
    const float* Wc   = (const float*)d_in[7];
    const float* bncs = (const float*)d_in[8];
    const float* bncb = (const float*)d_in[9];

    _Float16* w1g = (_Float16*)d_ws;   // 24576 f16 = 48 KiB

    prep_w1g<<<96, 256, 0, stream>>>(W1, w1g);
    fused_kernel<<<2048, 128, 0, stream>>>(x, W0, bn0s, bn0b, w1g,
                                           bn1s, bn1b, Wc, bncs, bncb,
                                           (float*)d_out);
}

// Round 7
// 166.278 us; speedup vs baseline: 3.8786x; 3.8786x over previous
//
#include <hip/hip_runtime.h>

#define NEGSLOPE 0.2f
#define NINF (-3.4e38f)

typedef _Float16 half8 __attribute__((ext_vector_type(8)));
typedef _Float16 half2v __attribute__((ext_vector_type(2)));
typedef float f32x4 __attribute__((ext_vector_type(4)));

#define YSTRIDE 72  // f16 units; row stride 144 B (16B-aligned for b128)

// ---------------------------------------------------------------------------
// prep: W1 (384,64) row-major -> B-fragment order for the K=384 fused GEMM.
// (unchanged, known-correct)
// ---------------------------------------------------------------------------
__global__ void prep_w1g(const float* __restrict__ w1, _Float16* __restrict__ w1g) {
    int tid = blockIdx.x * 256 + threadIdx.x;
    if (tid < 24576) {
        int j = tid & 7;
        int L = (tid >> 3) & 63;
        int r = tid >> 9;          // r = ks*4 + t4
        int t4 = r & 3;
        int ks = r >> 2;
        int q = L >> 4, c = L & 15;
        int i = ks >> 1;
        int o = 32 * (ks & 1) + 8 * q + j;
        int u = 16 * t4 + c;
        w1g[tid] = (_Float16)w1[(u * 6 + i) * 64 + o];
    }
}

// ---------------------------------------------------------------------------
// topk v5: one wave per row; key = ~bits(||xj-xn||^2). PER-LANE top-2 cache
// (u64 (key<<32)|~j) -- no groups. Self point (d=0 -> key 0xFFFFFFFF) is the
// guaranteed global winner: emitted directly as idx[0], its lane pre-demoted
// (self-skip; 19 extractions remain). Zap state = 32-bit zmask per lane;
// refill (rare, ~21% of rows) rescans the retained skh[32] under zmask.
// Wave argmax = 32-bit DPP max chain + ballot/ffs/readlane decode. Winner =
// first-ballot lane's top; only that lane demotes -> set-exact (downstream
// max over k is order-invariant).
// ---------------------------------------------------------------------------
template <int CTRL>
__device__ __forceinline__ unsigned dpp_mov(unsigned v) {
    return (unsigned)__builtin_amdgcn_update_dpp(0, (int)v, CTRL, 0xF, 0xF, false);
}

__global__ __launch_bounds__(256) void topk_kernel(const float* __restrict__ x,
                                                   int* __restrict__ idx_out) {
    const int wave = threadIdx.x >> 6;
    const int lane = threadIdx.x & 63;
    const int row = blockIdx.x * 4 + wave;
    const int b = row >> 11;
    const int n = row & 2047;
    const float* xb = x + b * 6144;
    const float xn0 = xb[n];
    const float xn1 = xb[2048 + n];
    const float xn2 = xb[4096 + n];

    unsigned skh[32];                 // key per candidate t (j = t*64+lane)
    unsigned long long g1 = 0ull, g2 = 0ull;  // per-lane top-2 (key<<32)|~j

#pragma unroll
    for (int t = 0; t < 32; ++t) {
        const int j = t * 64 + lane;
        const float dx = xb[j] - xn0;
        const float dy = xb[2048 + j] - xn1;
        const float dz = xb[4096 + j] - xn2;
        const float d = dx * dx + dy * dy + dz * dz;
        const unsigned s = ~__float_as_uint(d);
        skh[t] = s;
        const unsigned long long cand =
            ((unsigned long long)s << 32) | (unsigned)(~j);
        const bool cgt = cand > g1;
        const unsigned long long t2 = cgt ? g1 : cand;
        g1 = cgt ? cand : g1;
        if (t2 > g2) g2 = t2;
    }

    const int out_base = row * 20;

    // self-skip: d(self)=0 -> key 0xFFFFFFFF is the strict wave max.
    if (lane == 0) idx_out[out_base] = n;
    const bool selfLane = (lane == (n & 63));
    unsigned zmask = selfLane ? (1u << (n >> 6)) : 0u;
    if (selfLane) { g1 = g2; g2 = 0ull; }

    for (int k = 1; k < 20; ++k) {
        // 32-bit wave max of key via DPP; lands in lane 63
        unsigned m = (unsigned)(g1 >> 32);
        { unsigned o = dpp_mov<0x111>(m); m = o > m ? o : m; }  // row_shr:1
        { unsigned o = dpp_mov<0x112>(m); m = o > m ? o : m; }  // row_shr:2
        { unsigned o = dpp_mov<0x114>(m); m = o > m ? o : m; }  // row_shr:4
        { unsigned o = dpp_mov<0x118>(m); m = o > m ? o : m; }  // row_shr:8
        { unsigned o = dpp_mov<0x142>(m); m = o > m ? o : m; }  // row_bcast:15
        { unsigned o = dpp_mov<0x143>(m); m = o > m ? o : m; }  // row_bcast:31
        const unsigned K = (unsigned)__builtin_amdgcn_readlane((int)m, 63);
        const unsigned long long ball = __ballot((unsigned)(g1 >> 32) == K);
        const int Ls = __ffsll((unsigned long long)ball) - 1;
        const unsigned lo =
            (unsigned)__builtin_amdgcn_readlane((int)(unsigned)g1, Ls);
        const int bj = (int)~lo;       // wave-uniform winner index
        if (lane == 0) idx_out[out_base + k] = bj;

        if (k < 19) {
            const bool isL = (lane == Ls);
            zmask |= isL ? (1u << (bj >> 6)) : 0u;
            if (isL) { g1 = g2; g2 = 0ull; }
            // depletion check on the winner lane (wave-uniform branch)
            const unsigned h1 = (unsigned)(g1 >> 32);
            if (__builtin_amdgcn_readlane((int)h1, Ls) == 0) {
                // refill own top-2 from retained keys (idempotent for
                // non-winner lanes)
                unsigned long long n1 = 0ull, n2 = 0ull;
#pragma unroll
                for (int t = 0; t < 32; ++t) {
                    const unsigned sv = ((zmask >> t) & 1u) ? 0u : skh[t];
                    const unsigned long long cc =
                        ((unsigned long long)sv << 32) |
                        (unsigned)(~(t * 64 + lane));
                    const bool cg = cc > n1;
                    const unsigned long long tt = cg ? n1 : cc;
                    n1 = cg ? cc : n1;
                    if (tt > n2) n2 = tt;
                }
                g1 = n1;
                g2 = n2;
            }
        }
    }
}

// ---------------------------------------------------------------------------
// mlp via single K=384 MFMA GEMM (R5 structure) with the R6-verified
// XOR-swizzled y tile (o' = o ^ (edge & 0x38)): paired b32 LDS stores and
// swizzle-consistent ds_read_b128 A-fragments.
// ---------------------------------------------------------------------------
__global__ __launch_bounds__(128, 2) void mlp_mfma(
    const float* __restrict__ x, const int* __restrict__ idx,
    const float* __restrict__ w0, const float* __restrict__ bn0s,
    const float* __restrict__ bn0b, const _Float16* __restrict__ w1g,
    const float* __restrict__ bn1s, const float* __restrict__ bn1b,
    const float* __restrict__ wc, const float* __restrict__ bncs,
    const float* __restrict__ bncb, float* __restrict__ out) {
    __shared__ __align__(16) _Float16 yL[2][80 * YSTRIDE];
    __shared__ __align__(4) _Float16 ehL[2][6][80];
    const int wave = threadIdx.x >> 6;
    const int lane = threadIdx.x & 63;
    const int q = lane >> 4, c = lane & 15;
    const int gw = blockIdx.x * 2 + wave;     // 0..4095
    const int b = gw >> 9;                    // 512 waves per batch
    const int P0 = (gw & 511) * 4;
    const float* xb = x + b * 6144;
    _Float16* yw = yL[wave];
    _Float16(*ehw)[80] = ehL[wave];

    // ---- e-stage: lane <-> edge_local (and +64 for lanes<16) ----
    float e0[6], e1_[6];
    {
        const int k = lane >> 2, pt = lane & 3;
        const int n = P0 + pt;
        const int j = idx[(b * 2048 + n) * 20 + k];
        const float c0 = xb[n], c1 = xb[2048 + n], c2 = xb[4096 + n];
        e0[0] = xb[j] - c0; e0[1] = xb[2048 + j] - c1; e0[2] = xb[4096 + j] - c2;
        e0[3] = c0; e0[4] = c1; e0[5] = c2;
#pragma unroll
        for (int i = 0; i < 6; ++i) ehw[i][lane] = (_Float16)e0[i];
    }
#pragma unroll
    for (int i = 0; i < 6; ++i) e1_[i] = 0.f;
    if (lane < 16) {
        const int el = 64 + lane;
        const int k = el >> 2, pt = el & 3;
        const int n = P0 + pt;
        const int j = idx[(b * 2048 + n) * 20 + k];
        const float c0 = xb[n], c1 = xb[2048 + n], c2 = xb[4096 + n];
        e1_[0] = xb[j] - c0; e1_[1] = xb[2048 + j] - c1; e1_[2] = xb[4096 + j] - c2;
        e1_[3] = c0; e1_[4] = c1; e1_[5] = c2;
#pragma unroll
        for (int i = 0; i < 6; ++i) ehw[i][el] = (_Float16)e1_[i];
    }

    // ---- y-stage: lane = edge, o in pairs; swizzled b32 stores ----
    const int sw0 = lane & 0x38;
    const int sw1 = lane & 8;          // = (64+lane) & 0x38 for lane < 16
#pragma unroll 4
    for (int o = 0; o < 64; o += 2) {
        const float s0a = bn0s[o], b0a = bn0b[o];
        const float s0b = bn0s[o + 1], b0b = bn0b[o + 1];
        const float* wra = w0 + o * 6;
        const float* wrb = wra + 6;
        float ya = wra[0] * e0[0] + wra[1] * e0[1] + wra[2] * e0[2] +
                   wra[3] * e0[3] + wra[4] * e0[4] + wra[5] * e0[5];
        ya = ya * s0a + b0a; ya = fmaxf(ya, NEGSLOPE * ya);
        float yb = wrb[0] * e0[0] + wrb[1] * e0[1] + wrb[2] * e0[2] +
                   wrb[3] * e0[3] + wrb[4] * e0[4] + wrb[5] * e0[5];
        yb = yb * s0b + b0b; yb = fmaxf(yb, NEGSLOPE * yb);
        *(half2v*)&yw[lane * YSTRIDE + (o ^ sw0)] =
            (half2v){(_Float16)ya, (_Float16)yb};
        if (lane < 16) {
            float yc = wra[0] * e1_[0] + wra[1] * e1_[1] + wra[2] * e1_[2] +
                       wra[3] * e1_[3] + wra[4] * e1_[4] + wra[5] * e1_[5];
            yc = yc * s0a + b0a; yc = fmaxf(yc, NEGSLOPE * yc);
            float yd = wrb[0] * e1_[0] + wrb[1] * e1_[1] + wrb[2] * e1_[2] +
                       wrb[3] * e1_[3] + wrb[4] * e1_[4] + wrb[5] * e1_[5];
            yd = yd * s0b + b0b; yd = fmaxf(yd, NEGSLOPE * yd);
            *(half2v*)&yw[(64 + lane) * YSTRIDE + (o ^ sw1)] =
                (half2v){(_Float16)yc, (_Float16)yd};
        }
    }

    __syncthreads();

    const half8* w1g8 = (const half8*)w1g;

    f32x4 acc[5][4];  // [m][t4], u = 16*t4 + c, edge row = 4q + r
#pragma unroll
    for (int mm = 0; mm < 5; ++mm)
#pragma unroll
        for (int t4 = 0; t4 < 4; ++t4) acc[mm][t4] = (f32x4){0.f, 0.f, 0.f, 0.f};

    // ---- main loop: 12 k-steps as 6 x 2; swizzled A re-read per step ----
#pragma unroll 1
    for (int i6 = 0; i6 < 6; ++i6) {
        _Float16 es[5];
#pragma unroll
        for (int mm = 0; mm < 5; ++mm) es[mm] = ehw[i6][16 * mm + c];
#pragma unroll
        for (int ks2 = 0; ks2 < 2; ++ks2) {
            const int ks = 2 * i6 + ks2;
            half8 B[4];
#pragma unroll
            for (int t4 = 0; t4 < 4; ++t4)
                B[t4] = w1g8[(ks * 4 + t4) * 64 + lane];
#pragma unroll
            for (int mm = 0; mm < 5; ++mm) {
                const int rrow = 16 * mm + c;
                const half8 Af = *(const half8*)&yw[rrow * YSTRIDE +
                                                    ((32 * ks2 + 8 * q) ^ (rrow & 0x38))];
                const half8 An = Af * es[mm];
#pragma unroll
                for (int t4 = 0; t4 < 4; ++t4)
                    acc[mm][t4] = __builtin_amdgcn_mfma_f32_16x16x32_f16(
                        An, B[t4], acc[mm][t4], 0, 0, 0);
            }
        }
    }

    // ---- bn1 + leaky + max over k (k = 4m+q) ----
    float bs1[4], bb1[4];
#pragma unroll
    for (int t4 = 0; t4 < 4; ++t4) {
        bs1[t4] = bn1s[16 * t4 + c];
        bb1[t4] = bn1b[16 * t4 + c];
    }

    float x1[4][4];  // [pt r][t4]
#pragma unroll
    for (int r = 0; r < 4; ++r)
#pragma unroll
        for (int t4 = 0; t4 < 4; ++t4) {
            float v = NINF;
#pragma unroll
            for (int mm = 0; mm < 5; ++mm) {
                float w = acc[mm][t4][r] * bs1[t4] + bb1[t4];
                w = fmaxf(w, NEGSLOPE * w);
                v = fmaxf(v, w);
            }
            v = fmaxf(v, __shfl_xor(v, 16, 64));
            v = fmaxf(v, __shfl_xor(v, 32, 64));
            x1[r][t4] = v;
        }

    // ---- head: z[pt][co] = leaky(bnc(sum_u x1*wc)) ----
    float wcv[3][4];
#pragma unroll
    for (int co = 0; co < 3; ++co)
#pragma unroll
        for (int t4 = 0; t4 < 4; ++t4) wcv[co][t4] = wc[co * 64 + 16 * t4 + c];

    float part[4][3];
#pragma unroll
    for (int r = 0; r < 4; ++r)
#pragma unroll
        for (int co = 0; co < 3; ++co) {
            float s = x1[r][0] * wcv[co][0] + x1[r][1] * wcv[co][1] +
                      x1[r][2] * wcv[co][2] + x1[r][3] * wcv[co][3];
#pragma unroll
            for (int d = 1; d < 16; d <<= 1) s += __shfl_xor(s, d, 64);
            part[r][co] = s;
        }

    if (c == 0 && q < 3) {
        const float sc = bncs[q], bc = bncb[q];
#pragma unroll
        for (int r = 0; r < 4; ++r) {
            float z = part[r][q] * sc + bc;
            z = fmaxf(z, NEGSLOPE * z);
            out[(b * 3 + q) * 2048 + P0 + r] = z;
        }
    }
}

// ---------------------------------------------------------------------------
extern "C" void kernel_launch(void* const* d_in, const int* in_sizes, int n_in,
                              void* d_out, int out_size, void* d_ws, size_t ws_size,
                              hipStream_t stream) {
    const float* x    = (const float*)d_in[0];
    const float* W0   = (const float*)d_in[1];
    const float* bn0s = (const float*)d_in[2];
    const float* bn0b = (const float*)d_in[3];
    const float* W1   = (const float*)d_in[4];
    const float* bn1s = (const float*)d_in[5];
    const float* bn1b = (const float*)d_in[6];
    const float* Wc   = (const float*)d_in[7];
    const float* bncs = (const float*)d_in[8];
    const float* bncb = (const float*)d_in[9];

    _Float16* w1g = (_Float16*)d_ws;             // 24576 f16 = 48 KiB
    int* idx = (int*)((char*)d_ws + 65536);      // 16384*20 ints = 1.25 MiB

    prep_w1g<<<96, 256, 0, stream>>>(W1, w1g);
    topk_kernel<<<4096, 256, 0, stream>>>(x, idx);
    mlp_mfma<<<2048, 128, 0, stream>>>(x, idx, W0, bn0s, bn0b, w1g,
                                       bn1s, bn1b, Wc, bncs, bncb,
                                       (float*)d_out);
}